// Round 5
// baseline (136.344 us; speedup 1.0000x reference)
//
#include <hip/hip_runtime.h>
#include <hip/hip_bf16.h>
#include <stdint.h>

// x[L=512][N=64][D=512] f32, upfold[O=512][N=64][D=512] f32
//   S[l,o,n] = sum_d x[l,n,d]*up[o,n,d] / sqrt(512);  W = sigmoid(S)-0.5
//   out[l,n,d] = sum_o W[l,o,n] * up[o,n,d]   (f32)
//
// Full tier:
//   kPrepUp: up -> ub bf16 [n][o][d] + ut bf16 [n][d][o]
//   kPrepX : x  -> xb bf16 [n][l][d]
//   kGemmT<1>: W[n][l][o] = sig(xb . ub^T / sqrt(D)) - 0.5     (bf16)
//   kGemmT<2>: out[l][n][d] = W . ut^T                          (f32)
// GEMMs: 128x128 tile, BK=64, DEPTH-3 pipeline with COUNTED vmcnt(8)
// (T4: tile kt+2 issued before computing tile kt; wait only requires
// tile kt+1 done -> ~2 compute phases of load in-flight time),
// swizzled SOURCE + linear LDS dest + swizzled ds_read, XCD n-grouping.

typedef __attribute__((ext_vector_type(8))) short short8;   // 8 bf16
typedef __attribute__((ext_vector_type(4))) float f32x4;

__device__ __forceinline__ uint16_t f2bf(float f) {
    uint32_t u = __builtin_bit_cast(uint32_t, f);
    uint32_t r = u + 0x7FFFu + ((u >> 16) & 1u);   // RNE
    return (uint16_t)(r >> 16);
}
__device__ __forceinline__ uint32_t cvt2(float a, float b) {
    return (uint32_t)f2bf(a) | ((uint32_t)f2bf(b) << 16);
}

// ---------------- prep: ub[n][o][d] + ut[n][d][o] <- up[o][n][d] --------------
__global__ __launch_bounds__(256) void kPrepUp(const float* __restrict__ up,
                                               uint16_t* __restrict__ ub,
                                               uint16_t* __restrict__ ut) {
    __shared__ float tile[64][65];
    int b = blockIdx.x;              // 64 n * 64 tiles
    int n = b >> 6, r = b & 63;
    int o0 = (r >> 3) << 6, d0 = (r & 7) << 6;
    int tid = threadIdx.x;
    int i  = tid >> 2;               // 0..63
    int jq = (tid & 3) << 4;         // 0,16,32,48

    const float* src = up + ((size_t)(o0 + i) * 64 + n) * 512 + d0 + jq;
    float v[16];
    #pragma unroll
    for (int c = 0; c < 16; c += 4) {
        float4 q = *reinterpret_cast<const float4*>(src + c);
        v[c] = q.x; v[c+1] = q.y; v[c+2] = q.z; v[c+3] = q.w;
        tile[i][jq+c] = q.x; tile[i][jq+c+1] = q.y;
        tile[i][jq+c+2] = q.z; tile[i][jq+c+3] = q.w;
    }
    uint32_t pk[8];
    if (ub) {
        #pragma unroll
        for (int c = 0; c < 8; ++c) pk[c] = cvt2(v[2*c], v[2*c+1]);
        uint16_t* udst = ub + ((size_t)n * 512 + o0 + i) * 512 + d0 + jq;
        *reinterpret_cast<uint4*>(udst)     = *reinterpret_cast<const uint4*>(pk);
        *reinterpret_cast<uint4*>(udst + 8) = *reinterpret_cast<const uint4*>(pk + 4);
    }
    __syncthreads();
    #pragma unroll
    for (int c = 0; c < 8; ++c) pk[c] = cvt2(tile[jq + 2*c][i], tile[jq + 2*c + 1][i]);
    uint16_t* tdst = ut + ((size_t)n * 512 + d0 + i) * 512 + o0 + jq;
    *reinterpret_cast<uint4*>(tdst)     = *reinterpret_cast<const uint4*>(pk);
    *reinterpret_cast<uint4*>(tdst + 8) = *reinterpret_cast<const uint4*>(pk + 4);
}

// ---------------- prep: xb[n][l][d] bf16 <- x[l][n][d] f32 --------------------
__global__ __launch_bounds__(256) void kPrepX(const float* __restrict__ x,
                                              uint16_t* __restrict__ xb) {
    int b = blockIdx.x;
    int tid = threadIdx.x;
    int row = b * 4 + (tid >> 6);    // (l*64 + n)
    int l = row >> 6, n = row & 63;
    int d0 = (tid & 63) * 8;
    const float* src = x + (size_t)row * 512 + d0;
    float4 v0 = *reinterpret_cast<const float4*>(src);
    float4 v1 = *reinterpret_cast<const float4*>(src + 4);
    uint32_t pk[4] = {cvt2(v0.x, v0.y), cvt2(v0.z, v0.w),
                      cvt2(v1.x, v1.y), cvt2(v1.z, v1.w)};
    *reinterpret_cast<uint4*>(xb + ((size_t)n * 512 + l) * 512 + d0) =
        *reinterpret_cast<const uint4*>(pk);
}

// ---------------- GEMM template: C = A . B^T over panels [n][512][512] bf16 ---
// MODE 1: sigmoid epilogue -> W bf16 [n][l][o].  MODE 2: f32 -> out[l][n][d].
template<int MODE>
__global__ __launch_bounds__(256) void kGemmT(const uint16_t* __restrict__ A,
                                              const uint16_t* __restrict__ B,
                                              void* __restrict__ outp) {
    __shared__ uint16_t As[3][8192];          // [buf][128 rows x 64 k], 16KB each
    __shared__ uint16_t Bs[3][8192];
    int d = blockIdx.x;                       // XCD n-grouping
    int n  = (d & 7) * 8 + (d >> 7);
    int t  = (d >> 3) & 15;
    int l0 = (t >> 2) << 7, c0 = (t & 3) << 7;
    int tid = threadIdx.x, lane = tid & 63, wid = tid >> 6;
    int wr = wid >> 1, wc = wid & 1;

    const char* An = (const char*)(A + (size_t)n * 262144);
    const char* Bn = (const char*)(B + (size_t)n * 262144);
    int rsub  = lane >> 3;                    // row within 8-row group
    int sbyte = ((lane & 7) ^ rsub) << 4;     // swizzled source chunk
    const char* gA = An + (size_t)(l0 + wid * 32 + rsub) * 1024 + sbyte;
    const char* gB = Bn + (size_t)(c0 + wid * 32 + rsub) * 1024 + sbyte;

    f32x4 acc[4][4];
    #pragma unroll
    for (int m = 0; m < 4; ++m)
        #pragma unroll
        for (int nf = 0; nf < 4; ++nf) acc[m][nf] = (f32x4)(0.f);

    // stage one 128x64 K-tile (A+B, 8 gload_lds per wave) into buffer `buf`
    auto STAGE = [&](int buf, int kt) {
        const char* pA = gA + kt * 128;
        const char* pB = gB + kt * 128;
        uint16_t* lA = &As[buf][wid * 2048];
        uint16_t* lB = &Bs[buf][wid * 2048];
        #pragma unroll
        for (int j = 0; j < 4; ++j) {
            __builtin_amdgcn_global_load_lds(
                (const __attribute__((address_space(1))) uint32_t*)(pA + j * 8192),
                (__attribute__((address_space(3))) uint32_t*)(lA + j * 512), 16, 0, 0);
            __builtin_amdgcn_global_load_lds(
                (const __attribute__((address_space(1))) uint32_t*)(pB + j * 8192),
                (__attribute__((address_space(3))) uint32_t*)(lB + j * 512), 16, 0, 0);
        }
    };

    // prologue: fill buf0 and buf1; require only buf0 complete (8 newest fly)
    STAGE(0, 0);
    STAGE(1, 1);
    asm volatile("s_waitcnt vmcnt(8)" ::: "memory");
    __builtin_amdgcn_s_barrier();
    __builtin_amdgcn_sched_barrier(0);

    #pragma unroll
    for (int kt = 0; kt < 8; ++kt) {
        const int cur = kt % 3;
        if (kt < 6) STAGE((kt + 2) % 3, kt + 2);   // issue 2 tiles ahead
        // compute current tile
        #pragma unroll
        for (int kk = 0; kk < 2; ++kk) {
            short8 a[4], bb[4];
            int kbyte = kk * 64 + ((lane >> 4) * 16);
            #pragma unroll
            for (int m = 0; m < 4; ++m) {
                int row = wr * 64 + m * 16 + (lane & 15);
                int off = row * 128 + (kbyte ^ ((row & 7) << 4));
                a[m] = *reinterpret_cast<const short8*>((const char*)As[cur] + off);
            }
            #pragma unroll
            for (int nf = 0; nf < 4; ++nf) {
                int row = wc * 64 + nf * 16 + (lane & 15);
                int off = row * 128 + (kbyte ^ ((row & 7) << 4));
                bb[nf] = *reinterpret_cast<const short8*>((const char*)Bs[cur] + off);
            }
            #pragma unroll
            for (int m = 0; m < 4; ++m)
                #pragma unroll
                for (int nf = 0; nf < 4; ++nf)
                    acc[m][nf] = __builtin_amdgcn_mfma_f32_16x16x32_bf16(
                        a[m], bb[nf], acc[m][nf], 0, 0, 0);
        }
        // end-of-step: require tile kt+1 complete; allow tile kt+2's 8 in flight
        if (kt < 6) {
            asm volatile("s_waitcnt vmcnt(8)" ::: "memory");
            __builtin_amdgcn_s_barrier();
            __builtin_amdgcn_sched_barrier(0);
        } else if (kt == 6) {
            asm volatile("s_waitcnt vmcnt(0)" ::: "memory");
            __builtin_amdgcn_s_barrier();
            __builtin_amdgcn_sched_barrier(0);
        }
    }

    if constexpr (MODE == 1) {
        uint16_t* Wn = (uint16_t*)outp + (size_t)n * 262144;
        const float scale = 0.044194173824159216f;   // 1/sqrt(512)
        #pragma unroll
        for (int m = 0; m < 4; ++m) {
            int lrow0 = l0 + wr * 64 + m * 16 + ((lane >> 4) << 2);
            #pragma unroll
            for (int nf = 0; nf < 4; ++nf) {
                int ocol = c0 + wc * 64 + nf * 16 + (lane & 15);
                #pragma unroll
                for (int r = 0; r < 4; ++r) {
                    float aff = acc[m][nf][r] * scale;
                    float w = 1.f / (1.f + __expf(-aff)) - 0.5f;
                    Wn[(size_t)(lrow0 + r) * 512 + ocol] = f2bf(w);
                }
            }
        }
    } else {
        float* On = (float*)outp;
        #pragma unroll
        for (int m = 0; m < 4; ++m) {
            int lrow0 = l0 + wr * 64 + m * 16 + ((lane >> 4) << 2);
            #pragma unroll
            for (int nf = 0; nf < 4; ++nf) {
                int dcol = c0 + wc * 64 + nf * 16 + (lane & 15);
                #pragma unroll
                for (int r = 0; r < 4; ++r)
                    On[((size_t)(lrow0 + r) * 64 + n) * 512 + dcol] = acc[m][nf][r];
            }
        }
    }
}

// ---------------- mid tier GEMM1: f32 inputs, reg-staged ---------------------
__global__ __launch_bounds__(256) void kGemm1f32(const float* __restrict__ x,
                                                 const float* __restrict__ up,
                                                 uint16_t* __restrict__ W) {
    __shared__ uint16_t As[128 * 64];
    __shared__ uint16_t Bs[128 * 64];
    int b   = blockIdx.x;
    int n   = b >> 4;
    int t   = b & 15;
    int l0  = (t >> 2) << 7, o0 = (t & 3) << 7;
    int tid = threadIdx.x, lane = tid & 63, wid = tid >> 6;
    int wr = wid >> 1, wc = wid & 1;

    f32x4 acc[4][4];
    #pragma unroll
    for (int m = 0; m < 4; ++m)
        #pragma unroll
        for (int nf = 0; nf < 4; ++nf) acc[m][nf] = (f32x4)(0.f);

    int srow = tid >> 1;
    int kh   = (tid & 1) * 32;
    int swz  = (srow & 7) << 4;
    const float* aSrc = x  + ((size_t)(l0 + srow) * 64 + n) * 512 + kh;
    const float* bSrc = up + ((size_t)(o0 + srow) * 64 + n) * 512 + kh;

    for (int kt = 0; kt < 8; ++kt) {
        __syncthreads();
        const float* pA = aSrc + kt * 64;
        const float* pB = bSrc + kt * 64;
        #pragma unroll
        for (int c2 = 0; c2 < 4; ++c2) {
            float4 a0 = *reinterpret_cast<const float4*>(pA + c2 * 8);
            float4 a1 = *reinterpret_cast<const float4*>(pA + c2 * 8 + 4);
            float4 b0 = *reinterpret_cast<const float4*>(pB + c2 * 8);
            float4 b1 = *reinterpret_cast<const float4*>(pB + c2 * 8 + 4);
            uint32_t pa[4] = {cvt2(a0.x,a0.y), cvt2(a0.z,a0.w), cvt2(a1.x,a1.y), cvt2(a1.z,a1.w)};
            uint32_t pb[4] = {cvt2(b0.x,b0.y), cvt2(b0.z,b0.w), cvt2(b1.x,b1.y), cvt2(b1.z,b1.w)};
            int off = srow * 128 + (((kh * 2) + c2 * 16) ^ swz);
            *reinterpret_cast<uint4*>((char*)As + off) = *reinterpret_cast<const uint4*>(pa);
            *reinterpret_cast<uint4*>((char*)Bs + off) = *reinterpret_cast<const uint4*>(pb);
        }
        __syncthreads();
        #pragma unroll
        for (int kk = 0; kk < 2; ++kk) {
            short8 a[4], bf[4];
            int kbyte = kk * 64 + ((lane >> 4) * 16);
            #pragma unroll
            for (int m = 0; m < 4; ++m) {
                int row = wr * 64 + m * 16 + (lane & 15);
                int off = row * 128 + (kbyte ^ ((row & 7) << 4));
                a[m] = *reinterpret_cast<const short8*>((char*)As + off);
            }
            #pragma unroll
            for (int nf = 0; nf < 4; ++nf) {
                int row = wc * 64 + nf * 16 + (lane & 15);
                int off = row * 128 + (kbyte ^ ((row & 7) << 4));
                bf[nf] = *reinterpret_cast<const short8*>((char*)Bs + off);
            }
            #pragma unroll
            for (int m = 0; m < 4; ++m)
                #pragma unroll
                for (int nf = 0; nf < 4; ++nf)
                    acc[m][nf] = __builtin_amdgcn_mfma_f32_16x16x32_bf16(
                        a[m], bf[nf], acc[m][nf], 0, 0, 0);
        }
    }
    const float scale = 0.044194173824159216f;
    #pragma unroll
    for (int m = 0; m < 4; ++m) {
        int lrow0 = l0 + wr * 64 + m * 16 + ((lane >> 4) << 2);
        #pragma unroll
        for (int nf = 0; nf < 4; ++nf) {
            int ocol = o0 + wc * 64 + nf * 16 + (lane & 15);
            #pragma unroll
            for (int r = 0; r < 4; ++r) {
                float aff = acc[m][nf][r] * scale;
                float w = 1.f / (1.f + __expf(-aff)) - 0.5f;
                W[((size_t)n * 512 + (lrow0 + r)) * 512 + ocol] = f2bf(w);
            }
        }
    }
}

// ---------------- naive fallback ---------------------------------------------
__global__ __launch_bounds__(256) void kNaive(const float* __restrict__ x,
                                              const float* __restrict__ up,
                                              float* __restrict__ out) {
    __shared__ float xr[512];
    __shared__ float w[512];
    int b = blockIdx.x;
    int l = b >> 6, n = b & 63;
    int tid = threadIdx.x;
    const float* xrow = x + ((size_t)l * 64 + n) * 512;
    xr[tid] = xrow[tid];
    xr[tid + 256] = xrow[tid + 256];
    __syncthreads();
    const float scale = 0.044194173824159216f;
    #pragma unroll
    for (int oo = 0; oo < 2; ++oo) {
        int o = tid + oo * 256;
        const float* ur = up + ((size_t)o * 64 + n) * 512;
        float s = 0.f;
        for (int dd = 0; dd < 512; ++dd) s += xr[dd] * ur[dd];
        w[o] = 1.f / (1.f + __expf(-s * scale)) - 0.5f;
    }
    __syncthreads();
    #pragma unroll
    for (int dd = 0; dd < 2; ++dd) {
        int d = tid + dd * 256;
        float f = 0.f;
        for (int o = 0; o < 512; ++o)
            f += w[o] * up[((size_t)o * 64 + n) * 512 + d];
        out[((size_t)l * 64 + n) * 512 + d] = f;
    }
}

extern "C" void kernel_launch(void* const* d_in, const int* in_sizes, int n_in,
                              void* d_out, int out_size, void* d_ws, size_t ws_size,
                              hipStream_t stream) {
    const float* x  = (const float*)d_in[0];
    const float* up = (const float*)d_in[1];
    float* out = (float*)d_out;

    const size_t MB32 = (size_t)64 * 512 * 512 * 2;   // one bf16 panel set
    if (ws_size >= 4 * MB32) {
        uint16_t* XB = (uint16_t*)d_ws;
        uint16_t* UB = XB + 16777216;
        uint16_t* UT = UB + 16777216;
        uint16_t* W  = UT + 16777216;
        kPrepUp<<<4096, 256, 0, stream>>>(up, UB, UT);
        kPrepX <<<8192, 256, 0, stream>>>(x, XB);
        kGemmT<1><<<1024, 256, 0, stream>>>(XB, UB, W);
        kGemmT<2><<<1024, 256, 0, stream>>>(W, UT, out);
    } else if (ws_size >= 2 * MB32) {
        uint16_t* UT = (uint16_t*)d_ws;
        uint16_t* W  = UT + 16777216;
        kPrepUp<<<4096, 256, 0, stream>>>(up, nullptr, UT);
        kGemm1f32<<<1024, 256, 0, stream>>>(x, up, W);
        kGemmT<2><<<1024, 256, 0, stream>>>(W, UT, out);
    } else {
        kNaive<<<512 * 64, 256, 0, stream>>>(x, up, out);
    }
}

// Round 6
// 110.133 us; speedup vs baseline: 1.2380x; 1.2380x over previous
//
#include <hip/hip_runtime.h>
#include <hip/hip_bf16.h>
#include <stdint.h>

// x[L=512][N=64][D=512] f32, upfold[O=512][N=64][D=512] f32
//   S[l,o,n] = sum_d x[l,n,d]*up[o,n,d] / sqrt(512);  W = sigmoid(S)-0.5
//   out[l,n,d] = sum_o W[l,o,n] * up[o,n,d]   (f32)
//
// Full tier:
//   kPrepUp: up -> ub bf16 [n][o][d] + ut bf16 [n][d][o]
//   kPrepX : x  -> xb bf16 [n][l][d]
//   kGemm256<1>: W[n][l][o] = sig(xb . ub^T / sqrt(D)) - 0.5     (bf16)
//   kGemm256<2>: out[l][n][d] = W . ut^T                          (f32)
// GEMMs: 256x256 tile, 512 thr / 8 waves (2Mx4N, per-wave 128x64), BK=64,
// depth-2 LDS double-buffer (128KB), global_load_lds w=16 with swizzled
// SOURCE + linear LDS dest + swizzled ds_read, XCD n-grouping (8 n/XCD).
// 64 MFMA per wave per K-step vs 24 ds_read + 8 gload -> stage latency
// hidden under compute (round-5 lesson: intensity, not pipeline depth).

typedef __attribute__((ext_vector_type(8))) short short8;   // 8 bf16
typedef __attribute__((ext_vector_type(4))) float f32x4;

__device__ __forceinline__ uint16_t f2bf(float f) {
    uint32_t u = __builtin_bit_cast(uint32_t, f);
    uint32_t r = u + 0x7FFFu + ((u >> 16) & 1u);   // RNE
    return (uint16_t)(r >> 16);
}
__device__ __forceinline__ uint32_t cvt2(float a, float b) {
    return (uint32_t)f2bf(a) | ((uint32_t)f2bf(b) << 16);
}

// ---------------- prep: ub[n][o][d] + ut[n][d][o] <- up[o][n][d] --------------
__global__ __launch_bounds__(256) void kPrepUp(const float* __restrict__ up,
                                               uint16_t* __restrict__ ub,
                                               uint16_t* __restrict__ ut) {
    __shared__ float tile[64][65];
    int b = blockIdx.x;              // 64 n * 64 tiles
    int n = b >> 6, r = b & 63;
    int o0 = (r >> 3) << 6, d0 = (r & 7) << 6;
    int tid = threadIdx.x;
    int i  = tid >> 2;               // 0..63
    int jq = (tid & 3) << 4;         // 0,16,32,48

    const float* src = up + ((size_t)(o0 + i) * 64 + n) * 512 + d0 + jq;
    float v[16];
    #pragma unroll
    for (int c = 0; c < 16; c += 4) {
        float4 q = *reinterpret_cast<const float4*>(src + c);
        v[c] = q.x; v[c+1] = q.y; v[c+2] = q.z; v[c+3] = q.w;
        tile[i][jq+c] = q.x; tile[i][jq+c+1] = q.y;
        tile[i][jq+c+2] = q.z; tile[i][jq+c+3] = q.w;
    }
    uint32_t pk[8];
    if (ub) {
        #pragma unroll
        for (int c = 0; c < 8; ++c) pk[c] = cvt2(v[2*c], v[2*c+1]);
        uint16_t* udst = ub + ((size_t)n * 512 + o0 + i) * 512 + d0 + jq;
        *reinterpret_cast<uint4*>(udst)     = *reinterpret_cast<const uint4*>(pk);
        *reinterpret_cast<uint4*>(udst + 8) = *reinterpret_cast<const uint4*>(pk + 4);
    }
    __syncthreads();
    #pragma unroll
    for (int c = 0; c < 8; ++c) pk[c] = cvt2(tile[jq + 2*c][i], tile[jq + 2*c + 1][i]);
    uint16_t* tdst = ut + ((size_t)n * 512 + d0 + i) * 512 + o0 + jq;
    *reinterpret_cast<uint4*>(tdst)     = *reinterpret_cast<const uint4*>(pk);
    *reinterpret_cast<uint4*>(tdst + 8) = *reinterpret_cast<const uint4*>(pk + 4);
}

// ---------------- prep: xb[n][l][d] bf16 <- x[l][n][d] f32 --------------------
__global__ __launch_bounds__(256) void kPrepX(const float* __restrict__ x,
                                              uint16_t* __restrict__ xb) {
    int b = blockIdx.x;
    int tid = threadIdx.x;
    int row = b * 4 + (tid >> 6);    // (l*64 + n)
    int l = row >> 6, n = row & 63;
    int d0 = (tid & 63) * 8;
    const float* src = x + (size_t)row * 512 + d0;
    float4 v0 = *reinterpret_cast<const float4*>(src);
    float4 v1 = *reinterpret_cast<const float4*>(src + 4);
    uint32_t pk[4] = {cvt2(v0.x, v0.y), cvt2(v0.z, v0.w),
                      cvt2(v1.x, v1.y), cvt2(v1.z, v1.w)};
    *reinterpret_cast<uint4*>(xb + ((size_t)n * 512 + l) * 512 + d0) =
        *reinterpret_cast<const uint4*>(pk);
}

// ---------------- 256^2 GEMM: C = A . B^T over panels [n][512][512] bf16 ------
// MODE 1: sigmoid epilogue -> W bf16 [n][l][o].  MODE 2: f32 -> out[l][n][d].
template<int MODE>
__global__ __launch_bounds__(512) void kGemm256(const uint16_t* __restrict__ A,
                                                const uint16_t* __restrict__ B,
                                                void* __restrict__ outp) {
    __shared__ uint16_t As[2][16384];         // [buf][256 rows x 64 k] = 32KB/buf
    __shared__ uint16_t Bs[2][16384];
    int bid = blockIdx.x;                     // 256 blocks: XCD owns 8 n's
    int n  = (bid & 7) * 8 + (bid >> 5);
    int t  = (bid >> 3) & 3;
    int l0 = (t >> 1) << 8, c0 = (t & 1) << 8;
    int tid = threadIdx.x, lane = tid & 63, wid = tid >> 6;   // 8 waves
    int wr = wid >> 2, wc = wid & 3;          // 2M x 4N; per-wave out 128x64

    const char* An = (const char*)(A + (size_t)n * 262144);
    const char* Bn = (const char*)(B + (size_t)n * 262144);
    int rsub  = lane >> 3;                    // row within 8-row group
    int sbyte = ((lane & 7) ^ rsub) << 4;     // swizzled source chunk
    // wave wid stages rows [wid*32, wid*32+32) of both A and B tiles
    const char* gA = An + (size_t)(l0 + wid * 32 + rsub) * 1024 + sbyte;
    const char* gB = Bn + (size_t)(c0 + wid * 32 + rsub) * 1024 + sbyte;

    f32x4 acc[8][4];
    #pragma unroll
    for (int m = 0; m < 8; ++m)
        #pragma unroll
        for (int nf = 0; nf < 4; ++nf) acc[m][nf] = (f32x4)(0.f);

    // stage one 256x64 K-tile (A+B, 8 gload_lds/thread) into buffer `buf`
    auto STAGE = [&](int buf, int kt) {
        const char* pA = gA + kt * 128;
        const char* pB = gB + kt * 128;
        uint16_t* lA = &As[buf][wid * 2048];  // 32 rows * 64 k
        uint16_t* lB = &Bs[buf][wid * 2048];
        #pragma unroll
        for (int j = 0; j < 4; ++j) {
            __builtin_amdgcn_global_load_lds(
                (const __attribute__((address_space(1))) uint32_t*)(pA + j * 8192),
                (__attribute__((address_space(3))) uint32_t*)(lA + j * 512), 16, 0, 0);
            __builtin_amdgcn_global_load_lds(
                (const __attribute__((address_space(1))) uint32_t*)(pB + j * 8192),
                (__attribute__((address_space(3))) uint32_t*)(lB + j * 512), 16, 0, 0);
        }
    };

    STAGE(0, 0);
    asm volatile("s_waitcnt vmcnt(0)" ::: "memory");
    __builtin_amdgcn_s_barrier();

    for (int kt = 0; kt < 8; ++kt) {
        const int cur = kt & 1;
        if (kt < 7) STAGE(cur ^ 1, kt + 1);   // prefetch next tile (async)
        const uint16_t* Ac = As[cur];
        const uint16_t* Bc = Bs[cur];
        #pragma unroll
        for (int kk = 0; kk < 2; ++kk) {
            short8 a[8], bb[4];
            int kbyte = kk * 64 + ((lane >> 4) * 16);
            #pragma unroll
            for (int nf = 0; nf < 4; ++nf) {
                int row = wc * 64 + nf * 16 + (lane & 15);
                int off = row * 128 + (kbyte ^ ((row & 7) << 4));
                bb[nf] = *reinterpret_cast<const short8*>((const char*)Bc + off);
            }
            #pragma unroll
            for (int m = 0; m < 8; ++m) {
                int row = wr * 128 + m * 16 + (lane & 15);
                int off = row * 128 + (kbyte ^ ((row & 7) << 4));
                a[m] = *reinterpret_cast<const short8*>((const char*)Ac + off);
            }
            #pragma unroll
            for (int m = 0; m < 8; ++m)
                #pragma unroll
                for (int nf = 0; nf < 4; ++nf)
                    acc[m][nf] = __builtin_amdgcn_mfma_f32_16x16x32_bf16(
                        a[m], bb[nf], acc[m][nf], 0, 0, 0);
        }
        if (kt < 7) {
            // next tile's loads complete; all waves done reading buf[cur]
            asm volatile("s_waitcnt vmcnt(0)" ::: "memory");
            __builtin_amdgcn_s_barrier();
        }
    }

    if constexpr (MODE == 1) {
        uint16_t* Wn = (uint16_t*)outp + (size_t)n * 262144;
        const float scale = 0.044194173824159216f;   // 1/sqrt(512)
        #pragma unroll
        for (int m = 0; m < 8; ++m) {
            int lrow0 = l0 + wr * 128 + m * 16 + ((lane >> 4) << 2);
            #pragma unroll
            for (int nf = 0; nf < 4; ++nf) {
                int ocol = c0 + wc * 64 + nf * 16 + (lane & 15);
                #pragma unroll
                for (int r = 0; r < 4; ++r) {
                    float aff = acc[m][nf][r] * scale;
                    float w = 1.f / (1.f + __expf(-aff)) - 0.5f;
                    Wn[(size_t)(lrow0 + r) * 512 + ocol] = f2bf(w);
                }
            }
        }
    } else {
        float* On = (float*)outp;
        #pragma unroll
        for (int m = 0; m < 8; ++m) {
            int lrow0 = l0 + wr * 128 + m * 16 + ((lane >> 4) << 2);
            #pragma unroll
            for (int nf = 0; nf < 4; ++nf) {
                int dcol = c0 + wc * 64 + nf * 16 + (lane & 15);
                #pragma unroll
                for (int r = 0; r < 4; ++r)
                    On[((size_t)(lrow0 + r) * 64 + n) * 512 + dcol] = acc[m][nf][r];
            }
        }
    }
}

// ---------------- mid tier GEMM1: f32 inputs, reg-staged ---------------------
__global__ __launch_bounds__(256) void kGemm1f32(const float* __restrict__ x,
                                                 const float* __restrict__ up,
                                                 uint16_t* __restrict__ W) {
    __shared__ uint16_t As[128 * 64];
    __shared__ uint16_t Bs[128 * 64];
    int b   = blockIdx.x;
    int n   = b >> 4;
    int t   = b & 15;
    int l0  = (t >> 2) << 7, o0 = (t & 3) << 7;
    int tid = threadIdx.x, lane = tid & 63, wid = tid >> 6;
    int wr = wid >> 1, wc = wid & 1;

    f32x4 acc[4][4];
    #pragma unroll
    for (int m = 0; m < 4; ++m)
        #pragma unroll
        for (int nf = 0; nf < 4; ++nf) acc[m][nf] = (f32x4)(0.f);

    int srow = tid >> 1;
    int kh   = (tid & 1) * 32;
    int swz  = (srow & 7) << 4;
    const float* aSrc = x  + ((size_t)(l0 + srow) * 64 + n) * 512 + kh;
    const float* bSrc = up + ((size_t)(o0 + srow) * 64 + n) * 512 + kh;

    for (int kt = 0; kt < 8; ++kt) {
        __syncthreads();
        const float* pA = aSrc + kt * 64;
        const float* pB = bSrc + kt * 64;
        #pragma unroll
        for (int c2 = 0; c2 < 4; ++c2) {
            float4 a0 = *reinterpret_cast<const float4*>(pA + c2 * 8);
            float4 a1 = *reinterpret_cast<const float4*>(pA + c2 * 8 + 4);
            float4 b0 = *reinterpret_cast<const float4*>(pB + c2 * 8);
            float4 b1 = *reinterpret_cast<const float4*>(pB + c2 * 8 + 4);
            uint32_t pa[4] = {cvt2(a0.x,a0.y), cvt2(a0.z,a0.w), cvt2(a1.x,a1.y), cvt2(a1.z,a1.w)};
            uint32_t pb[4] = {cvt2(b0.x,b0.y), cvt2(b0.z,b0.w), cvt2(b1.x,b1.y), cvt2(b1.z,b1.w)};
            int off = srow * 128 + (((kh * 2) + c2 * 16) ^ swz);
            *reinterpret_cast<uint4*>((char*)As + off) = *reinterpret_cast<const uint4*>(pa);
            *reinterpret_cast<uint4*>((char*)Bs + off) = *reinterpret_cast<const uint4*>(pb);
        }
        __syncthreads();
        #pragma unroll
        for (int kk = 0; kk < 2; ++kk) {
            short8 a[4], bf[4];
            int kbyte = kk * 64 + ((lane >> 4) * 16);
            #pragma unroll
            for (int m = 0; m < 4; ++m) {
                int row = wr * 64 + m * 16 + (lane & 15);
                int off = row * 128 + (kbyte ^ ((row & 7) << 4));
                a[m] = *reinterpret_cast<const short8*>((char*)As + off);
            }
            #pragma unroll
            for (int nf = 0; nf < 4; ++nf) {
                int row = wc * 64 + nf * 16 + (lane & 15);
                int off = row * 128 + (kbyte ^ ((row & 7) << 4));
                bf[nf] = *reinterpret_cast<const short8*>((char*)Bs + off);
            }
            #pragma unroll
            for (int m = 0; m < 4; ++m)
                #pragma unroll
                for (int nf = 0; nf < 4; ++nf)
                    acc[m][nf] = __builtin_amdgcn_mfma_f32_16x16x32_bf16(
                        a[m], bf[nf], acc[m][nf], 0, 0, 0);
        }
    }
    const float scale = 0.044194173824159216f;
    #pragma unroll
    for (int m = 0; m < 4; ++m) {
        int lrow0 = l0 + wr * 64 + m * 16 + ((lane >> 4) << 2);
        #pragma unroll
        for (int nf = 0; nf < 4; ++nf) {
            int ocol = o0 + wc * 64 + nf * 16 + (lane & 15);
            #pragma unroll
            for (int r = 0; r < 4; ++r) {
                float aff = acc[m][nf][r] * scale;
                float w = 1.f / (1.f + __expf(-aff)) - 0.5f;
                W[((size_t)n * 512 + (lrow0 + r)) * 512 + ocol] = f2bf(w);
            }
        }
    }
}

// ---------------- mid tier GEMM2 (128^2, single-buffer) ----------------------
__global__ __launch_bounds__(256) void kGemm2Mid(const uint16_t* __restrict__ W,
                                                 const uint16_t* __restrict__ ut,
                                                 float* __restrict__ out) {
    __shared__ uint16_t As[8192];
    __shared__ uint16_t Bs[8192];
    int d = blockIdx.x;
    int n  = (d & 7) * 8 + (d >> 7);
    int t  = (d >> 3) & 15;
    int l0 = (t >> 2) << 7, c0 = (t & 3) << 7;
    int tid = threadIdx.x, lane = tid & 63, wid = tid >> 6;
    int wr = wid >> 1, wc = wid & 1;

    const char* An = (const char*)(W  + (size_t)n * 262144);
    const char* Bn = (const char*)(ut + (size_t)n * 262144);
    int rsub  = lane >> 3;
    int sbyte = ((lane & 7) ^ rsub) << 4;
    const char* gA = An + (size_t)(l0 + wid * 32 + rsub) * 1024 + sbyte;
    const char* gB = Bn + (size_t)(c0 + wid * 32 + rsub) * 1024 + sbyte;
    uint16_t* lA = As + wid * 2048;
    uint16_t* lB = Bs + wid * 2048;

    f32x4 acc[4][4];
    #pragma unroll
    for (int m = 0; m < 4; ++m)
        #pragma unroll
        for (int nf = 0; nf < 4; ++nf) acc[m][nf] = (f32x4)(0.f);

    for (int kt = 0; kt < 8; ++kt) {
        if (kt) __syncthreads();
        #pragma unroll
        for (int j = 0; j < 4; ++j) {
            __builtin_amdgcn_global_load_lds(
                (const __attribute__((address_space(1))) uint32_t*)(gA + kt * 128 + j * 8192),
                (__attribute__((address_space(3))) uint32_t*)(lA + j * 512), 16, 0, 0);
            __builtin_amdgcn_global_load_lds(
                (const __attribute__((address_space(1))) uint32_t*)(gB + kt * 128 + j * 8192),
                (__attribute__((address_space(3))) uint32_t*)(lB + j * 512), 16, 0, 0);
        }
        __syncthreads();
        #pragma unroll
        for (int kk = 0; kk < 2; ++kk) {
            short8 a[4], bb[4];
            int kbyte = kk * 64 + ((lane >> 4) * 16);
            #pragma unroll
            for (int m = 0; m < 4; ++m) {
                int row = wr * 64 + m * 16 + (lane & 15);
                int off = row * 128 + (kbyte ^ ((row & 7) << 4));
                a[m] = *reinterpret_cast<const short8*>((const char*)As + off);
            }
            #pragma unroll
            for (int nf = 0; nf < 4; ++nf) {
                int row = wc * 64 + nf * 16 + (lane & 15);
                int off = row * 128 + (kbyte ^ ((row & 7) << 4));
                bb[nf] = *reinterpret_cast<const short8*>((const char*)Bs + off);
            }
            #pragma unroll
            for (int m = 0; m < 4; ++m)
                #pragma unroll
                for (int nf = 0; nf < 4; ++nf)
                    acc[m][nf] = __builtin_amdgcn_mfma_f32_16x16x32_bf16(
                        a[m], bb[nf], acc[m][nf], 0, 0, 0);
        }
    }
    #pragma unroll
    for (int m = 0; m < 4; ++m) {
        int lrow0 = l0 + wr * 64 + m * 16 + ((lane >> 4) << 2);
        #pragma unroll
        for (int nf = 0; nf < 4; ++nf) {
            int dcol = c0 + wc * 64 + nf * 16 + (lane & 15);
            #pragma unroll
            for (int r = 0; r < 4; ++r)
                out[((size_t)(lrow0 + r) * 64 + n) * 512 + dcol] = acc[m][nf][r];
        }
    }
}

// ---------------- naive fallback ---------------------------------------------
__global__ __launch_bounds__(256) void kNaive(const float* __restrict__ x,
                                              const float* __restrict__ up,
                                              float* __restrict__ out) {
    __shared__ float xr[512];
    __shared__ float w[512];
    int b = blockIdx.x;
    int l = b >> 6, n = b & 63;
    int tid = threadIdx.x;
    const float* xrow = x + ((size_t)l * 64 + n) * 512;
    xr[tid] = xrow[tid];
    xr[tid + 256] = xrow[tid + 256];
    __syncthreads();
    const float scale = 0.044194173824159216f;
    #pragma unroll
    for (int oo = 0; oo < 2; ++oo) {
        int o = tid + oo * 256;
        const float* ur = up + ((size_t)o * 64 + n) * 512;
        float s = 0.f;
        for (int dd = 0; dd < 512; ++dd) s += xr[dd] * ur[dd];
        w[o] = 1.f / (1.f + __expf(-s * scale)) - 0.5f;
    }
    __syncthreads();
    #pragma unroll
    for (int dd = 0; dd < 2; ++dd) {
        int d = tid + dd * 256;
        float f = 0.f;
        for (int o = 0; o < 512; ++o)
            f += w[o] * up[((size_t)o * 64 + n) * 512 + d];
        out[((size_t)l * 64 + n) * 512 + d] = f;
    }
}

extern "C" void kernel_launch(void* const* d_in, const int* in_sizes, int n_in,
                              void* d_out, int out_size, void* d_ws, size_t ws_size,
                              hipStream_t stream) {
    const float* x  = (const float*)d_in[0];
    const float* up = (const float*)d_in[1];
    float* out = (float*)d_out;

    const size_t MB32 = (size_t)64 * 512 * 512 * 2;   // one bf16 panel set
    if (ws_size >= 4 * MB32) {
        uint16_t* XB = (uint16_t*)d_ws;
        uint16_t* UB = XB + 16777216;
        uint16_t* UT = UB + 16777216;
        uint16_t* W  = UT + 16777216;
        kPrepUp<<<4096, 256, 0, stream>>>(up, UB, UT);
        kPrepX <<<8192, 256, 0, stream>>>(x, XB);
        kGemm256<1><<<256, 512, 0, stream>>>(XB, UB, W);
        kGemm256<2><<<256, 512, 0, stream>>>(W, UT, out);
    } else if (ws_size >= 2 * MB32) {
        uint16_t* UT = (uint16_t*)d_ws;
        uint16_t* W  = UT + 16777216;
        kPrepUp<<<4096, 256, 0, stream>>>(up, nullptr, UT);
        kGemm1f32<<<1024, 256, 0, stream>>>(x, up, W);
        kGemm2Mid<<<1024, 256, 0, stream>>>(W, UT, out);
    } else {
        kNaive<<<512 * 64, 256, 0, stream>>>(x, up, out);
    }
}